// Round 3
// baseline (220.239 us; speedup 1.0000x reference)
//
#include <hip/hip_runtime.h>

typedef __attribute__((ext_vector_type(8))) short short8;
typedef __attribute__((ext_vector_type(4))) float f32x4;

#define D128 128

// fp32 -> bf16 round-to-nearest-even (bit pattern)
__device__ __forceinline__ unsigned short f2bf(float f) {
    unsigned int u = __float_as_uint(f);
    u += 0x7fffu + ((u >> 16) & 1u);
    return (unsigned short)(u >> 16);
}

// ---------------------------------------------------------------------------
// Pre-kernel: convert W (fp32 [k=128][col=128]) into bf16 B-fragments in ws.
// fragment f = cf*4+kk; lane l holds 8 bf16 at ws[(f*64+l)*8] =
// B[k = kk*32 + (l>>4)*8 + j][col = cf*16 + (l&15)]
// ---------------------------------------------------------------------------
__global__ __launch_bounds__(64)
void convert_w_kernel(const float* __restrict__ w, unsigned short* __restrict__ wsb) {
    int t = blockIdx.x * 64 + threadIdx.x;   // 0..2047
    int f = t >> 6;
    int l = t & 63;
    int cf = f >> 2, kk = f & 3;
    int col   = cf * 16 + (l & 15);
    int kbase = kk * 32 + (l >> 4) * 8;
    short8 v;
    #pragma unroll
    for (int j = 0; j < 8; ++j)
        v[j] = (short)f2bf(w[(kbase + j) * D128 + col]);
    *(short8*)(wsb + (size_t)t * 8) = v;
}

// ---------------------------------------------------------------------------
// Main kernel: no LDS. Block = 4 waves x 32 rows = 128 rows.
// Nontemporal stores for `out` (write-once, never re-read) keep x L3-resident.
// ---------------------------------------------------------------------------
__global__ __launch_bounds__(256, 6)
void fused_linear_ln_kernel(const float* __restrict__ x,
                            const unsigned short* __restrict__ wsb,
                            const float* __restrict__ bias,
                            float* __restrict__ out)
{
    const int tid  = threadIdx.x;
    const int lane = tid & 63;
    const int wave = tid >> 6;
    const int lrow = lane & 15;
    const int lk   = lane >> 4;

    const long row_base = (long)blockIdx.x * 128 + wave * 32;

    float bias_v[8];
    #pragma unroll
    for (int cf = 0; cf < 8; ++cf) bias_v[cf] = bias[cf * 16 + lrow];

    // ---- load A rows (fp32) and convert to bf16 fragments ----
    short8 afrag[2][4];
    #pragma unroll
    for (int i = 0; i < 2; ++i) {
        const float* rp = x + (row_base + i * 16 + lrow) * D128 + lk * 8;
        #pragma unroll
        for (int kk = 0; kk < 4; ++kk) {
            const float4* p = (const float4*)(rp + kk * 32);
            float4 v0 = p[0];
            float4 v1 = p[1];
            short8 a;
            a[0] = (short)f2bf(v0.x); a[1] = (short)f2bf(v0.y);
            a[2] = (short)f2bf(v0.z); a[3] = (short)f2bf(v0.w);
            a[4] = (short)f2bf(v1.x); a[5] = (short)f2bf(v1.y);
            a[6] = (short)f2bf(v1.z); a[7] = (short)f2bf(v1.w);
            afrag[i][kk] = a;
        }
    }

    // ---- MFMA main loop ----
    f32x4 acc[2][8];
    #pragma unroll
    for (int i = 0; i < 2; ++i)
        #pragma unroll
        for (int cf = 0; cf < 8; ++cf) acc[i][cf] = (f32x4){0.f, 0.f, 0.f, 0.f};

    #pragma unroll
    for (int kk = 0; kk < 4; ++kk) {
        short8 bfrag[8];
        #pragma unroll
        for (int cf = 0; cf < 8; ++cf)
            bfrag[cf] = *(const short8*)(wsb + (size_t)((cf * 4 + kk) * 64 + lane) * 8);
        #pragma unroll
        for (int i = 0; i < 2; ++i)
            #pragma unroll
            for (int cf = 0; cf < 8; ++cf)
                acc[i][cf] = __builtin_amdgcn_mfma_f32_16x16x32_bf16(
                    afrag[i][kk], bfrag[cf], acc[i][cf], 0, 0, 0);
    }

    // ---- epilogue: + bias, per-row layernorm, nontemporal store ----
    #pragma unroll
    for (int i = 0; i < 2; ++i) {
        #pragma unroll
        for (int cf = 0; cf < 8; ++cf)
            #pragma unroll
            for (int r = 0; r < 4; ++r) acc[i][cf][r] += bias_v[cf];

        #pragma unroll
        for (int r = 0; r < 4; ++r) {
            float s = 0.f, q = 0.f;
            #pragma unroll
            for (int cf = 0; cf < 8; ++cf) {
                float z = acc[i][cf][r];
                s += z;
                q += z * z;
            }
            #pragma unroll
            for (int m = 1; m <= 8; m <<= 1) {
                s += __shfl_xor(s, m, 64);
                q += __shfl_xor(q, m, 64);
            }
            float mean = s * (1.0f / 128.0f);
            float var  = q * (1.0f / 128.0f) - mean * mean;
            float rs   = rsqrtf(var + 1e-5f);

            long row = row_base + i * 16 + lk * 4 + r;
            float* op = out + row * D128 + lrow;
            #pragma unroll
            for (int cf = 0; cf < 8; ++cf)
                __builtin_nontemporal_store((acc[i][cf][r] - mean) * rs, op + cf * 16);
        }
    }
}

extern "C" void kernel_launch(void* const* d_in, const int* in_sizes, int n_in,
                              void* d_out, int out_size, void* d_ws, size_t ws_size,
                              hipStream_t stream) {
    const float* x    = (const float*)d_in[0];
    const float* w    = (const float*)d_in[1];
    const float* bias = (const float*)d_in[2];
    float* out        = (float*)d_out;

    int nrows = in_sizes[0] / D128;
    int grid  = nrows / D128;

    unsigned short* wsb = (unsigned short*)d_ws;
    hipLaunchKernelGGL(convert_w_kernel, dim3(32), dim3(64), 0, stream, w, wsb);
    hipLaunchKernelGGL(fused_linear_ln_kernel, dim3(grid), dim3(256), 0, stream,
                       x, wsb, bias, out);
}

// Round 4
// 64.212 us; speedup vs baseline: 3.4299x; 3.4299x over previous
//
#include <hip/hip_runtime.h>

typedef __attribute__((ext_vector_type(8))) short short8;
typedef __attribute__((ext_vector_type(4))) float f32x4;

#define D128 128

// fp32 -> bf16 round-to-nearest-even (bit pattern)
__device__ __forceinline__ unsigned short f2bf(float f) {
    unsigned int u = __float_as_uint(f);
    u += 0x7fffu + ((u >> 16) & 1u);
    return (unsigned short)(u >> 16);
}

// ---------------------------------------------------------------------------
// Pre-kernel: convert W (fp32 [k=128][col=128]) into bf16 B-fragments in ws.
// fragment f = cf*4+kk; lane l holds 8 bf16 at ws[(f*64+l)*8] =
// B[k = kk*32 + (l>>4)*8 + j][col = cf*16 + (l&15)]
// ---------------------------------------------------------------------------
__global__ __launch_bounds__(64)
void convert_w_kernel(const float* __restrict__ w, unsigned short* __restrict__ wsb) {
    int t = blockIdx.x * 64 + threadIdx.x;   // 0..2047
    int f = t >> 6;
    int l = t & 63;
    int cf = f >> 2, kk = f & 3;
    int col   = cf * 16 + (l & 15);
    int kbase = kk * 32 + (l >> 4) * 8;
    short8 v;
    #pragma unroll
    for (int j = 0; j < 8; ++j)
        v[j] = (short)f2bf(w[(kbase + j) * D128 + col]);
    *(short8*)(wsb + (size_t)t * 8) = v;
}

// ---------------------------------------------------------------------------
// Main kernel: no LDS, software-pipelined across tiles within each wave.
// Block = 4 waves x 32 rows = 128 rows per tile; each block walks tiles
// grid-stride. Tile t+1's raw A loads are issued right after tile t's cvt,
// so MFMA+epilogue+stores of tile t hide the load latency of t+1.
// ---------------------------------------------------------------------------
__global__ __launch_bounds__(256)
void fused_linear_ln_kernel(const float* __restrict__ x,
                            const unsigned short* __restrict__ wsb,
                            const float* __restrict__ bias,
                            float* __restrict__ out,
                            int ntiles)
{
    const int tid  = threadIdx.x;
    const int lane = tid & 63;
    const int wave = tid >> 6;
    const int lrow = lane & 15;
    const int lk   = lane >> 4;
    const int gstride = gridDim.x;

    float bias_v[8];
    #pragma unroll
    for (int cf = 0; cf < 8; ++cf) bias_v[cf] = bias[cf * 16 + lrow];

    // raw A buffer: [i][kk][h] -> 16 float4
    float4 raw[2][4][2];

    // ---- issue loads for first tile ----
    {
        long rb = (long)blockIdx.x * 128 + wave * 32;
        #pragma unroll
        for (int i = 0; i < 2; ++i) {
            const float* rp = x + (rb + i * 16 + lrow) * D128 + lk * 8;
            #pragma unroll
            for (int kk = 0; kk < 4; ++kk) {
                const float4* p = (const float4*)(rp + kk * 32);
                raw[i][kk][0] = p[0];
                raw[i][kk][1] = p[1];
            }
        }
    }

    for (long t = blockIdx.x; t < ntiles; t += gstride) {
        const long row_base = t * 128 + wave * 32;

        // ---- cvt raw -> bf16 A fragments (consumes raw) ----
        short8 afrag[2][4];
        #pragma unroll
        for (int i = 0; i < 2; ++i) {
            #pragma unroll
            for (int kk = 0; kk < 4; ++kk) {
                float4 v0 = raw[i][kk][0];
                float4 v1 = raw[i][kk][1];
                short8 a;
                a[0] = (short)f2bf(v0.x); a[1] = (short)f2bf(v0.y);
                a[2] = (short)f2bf(v0.z); a[3] = (short)f2bf(v0.w);
                a[4] = (short)f2bf(v1.x); a[5] = (short)f2bf(v1.y);
                a[6] = (short)f2bf(v1.z); a[7] = (short)f2bf(v1.w);
                afrag[i][kk] = a;
            }
        }

        // ---- issue next tile's loads (overlap with MFMA + epilogue below) ----
        long tn = t + gstride;
        if (tn < ntiles) {
            long rb = tn * 128 + wave * 32;
            #pragma unroll
            for (int i = 0; i < 2; ++i) {
                const float* rp = x + (rb + i * 16 + lrow) * D128 + lk * 8;
                #pragma unroll
                for (int kk = 0; kk < 4; ++kk) {
                    const float4* p = (const float4*)(rp + kk * 32);
                    raw[i][kk][0] = p[0];
                    raw[i][kk][1] = p[1];
                }
            }
        }

        // ---- MFMA ----
        f32x4 acc[2][8];
        #pragma unroll
        for (int i = 0; i < 2; ++i)
            #pragma unroll
            for (int cf = 0; cf < 8; ++cf) acc[i][cf] = (f32x4){0.f, 0.f, 0.f, 0.f};

        #pragma unroll
        for (int kk = 0; kk < 4; ++kk) {
            short8 bfrag[8];
            #pragma unroll
            for (int cf = 0; cf < 8; ++cf)
                bfrag[cf] = *(const short8*)(wsb + (size_t)((cf * 4 + kk) * 64 + lane) * 8);
            #pragma unroll
            for (int i = 0; i < 2; ++i)
                #pragma unroll
                for (int cf = 0; cf < 8; ++cf)
                    acc[i][cf] = __builtin_amdgcn_mfma_f32_16x16x32_bf16(
                        afrag[i][kk], bfrag[cf], acc[i][cf], 0, 0, 0);
        }

        // ---- epilogue: + bias, per-row layernorm, store ----
        #pragma unroll
        for (int i = 0; i < 2; ++i) {
            #pragma unroll
            for (int cf = 0; cf < 8; ++cf)
                #pragma unroll
                for (int r = 0; r < 4; ++r) acc[i][cf][r] += bias_v[cf];

            #pragma unroll
            for (int r = 0; r < 4; ++r) {
                float s = 0.f, q = 0.f;
                #pragma unroll
                for (int cf = 0; cf < 8; ++cf) {
                    float z = acc[i][cf][r];
                    s += z;
                    q += z * z;
                }
                #pragma unroll
                for (int m = 1; m <= 8; m <<= 1) {
                    s += __shfl_xor(s, m, 64);
                    q += __shfl_xor(q, m, 64);
                }
                float mean = s * (1.0f / 128.0f);
                float var  = q * (1.0f / 128.0f) - mean * mean;
                float rs   = rsqrtf(var + 1e-5f);

                long row = row_base + i * 16 + lk * 4 + r;
                float* op = out + row * D128 + lrow;
                #pragma unroll
                for (int cf = 0; cf < 8; ++cf)
                    op[cf * 16] = (acc[i][cf][r] - mean) * rs;
            }
        }
    }
}

extern "C" void kernel_launch(void* const* d_in, const int* in_sizes, int n_in,
                              void* d_out, int out_size, void* d_ws, size_t ws_size,
                              hipStream_t stream) {
    const float* x    = (const float*)d_in[0];
    const float* w    = (const float*)d_in[1];
    const float* bias = (const float*)d_in[2];
    float* out        = (float*)d_out;

    int nrows  = in_sizes[0] / D128;   // 262144
    int ntiles = nrows / 128;          // 2048
    int grid   = ntiles / 2;           // 1024 blocks, 2 tiles each

    unsigned short* wsb = (unsigned short*)d_ws;
    hipLaunchKernelGGL(convert_w_kernel, dim3(32), dim3(64), 0, stream, w, wsb);
    hipLaunchKernelGGL(fused_linear_ln_kernel, dim3(grid), dim3(256), 0, stream,
                       x, wsb, bias, out, ntiles);
}

// Round 6
// 62.100 us; speedup vs baseline: 3.5465x; 1.0340x over previous
//
#include <hip/hip_runtime.h>

typedef __attribute__((ext_vector_type(8))) short short8;
typedef __attribute__((ext_vector_type(4))) float f32x4;

#define D128 128
#define TSTRIDE 132   // 16-row f32 transpose tile row stride: 132*4=528B, 16B-aligned, banks shift by 4/row

// fp32 -> bf16 round-to-nearest-even (bit pattern)
__device__ __forceinline__ unsigned short f2bf(float f) {
    unsigned int u = __float_as_uint(f);
    u += 0x7fffu + ((u >> 16) & 1u);
    return (unsigned short)(u >> 16);
}

// ---------------------------------------------------------------------------
// Pre-kernel: convert W (fp32 [k=128][col=128]) into bf16 B-fragments in ws.
// fragment f = cf*4+kk; lane l holds 8 bf16 at ws[(f*64+l)*8] =
// B[k = kk*32 + (l>>4)*8 + j][col = cf*16 + (l&15)]
// ---------------------------------------------------------------------------
__global__ __launch_bounds__(64)
void convert_w_kernel(const float* __restrict__ w, unsigned short* __restrict__ wsb) {
    int t = blockIdx.x * 64 + threadIdx.x;   // 0..2047
    int f = t >> 6;
    int l = t & 63;
    int cf = f >> 2, kk = f & 3;
    int col   = cf * 16 + (l & 15);
    int kbase = kk * 32 + (l >> 4) * 8;
    short8 v;
    #pragma unroll
    for (int j = 0; j < 8; ++j)
        v[j] = (short)f2bf(w[(kbase + j) * D128 + col]);
    *(short8*)(wsb + (size_t)t * 8) = v;
}

// ---------------------------------------------------------------------------
// Main kernel. Block = 4 waves x 32 rows = 128 rows/tile, grid-stride with
// next-tile load prefetch. Epilogue transposes each wave's 16x128 output
// block through its OWN LDS region (no barriers) so global stores become
// fully-coalesced 1KB dwordx4 wave-stores (previous scalar stores were
// 64-way line-divergent -> TA address-processing floor of ~80us).
// ---------------------------------------------------------------------------
__global__ __launch_bounds__(256)
void fused_linear_ln_kernel(const float* __restrict__ x,
                            const unsigned short* __restrict__ wsb,
                            const float* __restrict__ bias,
                            float* __restrict__ out,
                            int ntiles)
{
    __shared__ float tl[4][16][TSTRIDE];   // 33792 B, one 16x128(+pad) tile per wave

    const int tid  = threadIdx.x;
    const int lane = tid & 63;
    const int wave = tid >> 6;
    const int lrow = lane & 15;
    const int lk   = lane >> 4;
    const int gstride = gridDim.x;

    float bias_v[8];
    #pragma unroll
    for (int cf = 0; cf < 8; ++cf) bias_v[cf] = bias[cf * 16 + lrow];

    // raw A buffer: [i][kk][h] -> 16 float4
    float4 raw[2][4][2];

    // ---- issue loads for first tile ----
    {
        long rb = (long)blockIdx.x * 128 + wave * 32;
        #pragma unroll
        for (int i = 0; i < 2; ++i) {
            const float* rp = x + (rb + i * 16 + lrow) * D128 + lk * 8;
            #pragma unroll
            for (int kk = 0; kk < 4; ++kk) {
                const float4* p = (const float4*)(rp + kk * 32);
                raw[i][kk][0] = p[0];
                raw[i][kk][1] = p[1];
            }
        }
    }

    for (long t = blockIdx.x; t < ntiles; t += gstride) {
        const long row_base = t * 128 + wave * 32;

        // ---- cvt raw -> bf16 A fragments ----
        short8 afrag[2][4];
        #pragma unroll
        for (int i = 0; i < 2; ++i) {
            #pragma unroll
            for (int kk = 0; kk < 4; ++kk) {
                float4 v0 = raw[i][kk][0];
                float4 v1 = raw[i][kk][1];
                short8 a;
                a[0] = (short)f2bf(v0.x); a[1] = (short)f2bf(v0.y);
                a[2] = (short)f2bf(v0.z); a[3] = (short)f2bf(v0.w);
                a[4] = (short)f2bf(v1.x); a[5] = (short)f2bf(v1.y);
                a[6] = (short)f2bf(v1.z); a[7] = (short)f2bf(v1.w);
                afrag[i][kk] = a;
            }
        }

        // ---- issue next tile's loads (hidden under MFMA + epilogue) ----
        long tn = t + gstride;
        if (tn < ntiles) {
            long rb = tn * 128 + wave * 32;
            #pragma unroll
            for (int i = 0; i < 2; ++i) {
                const float* rp = x + (rb + i * 16 + lrow) * D128 + lk * 8;
                #pragma unroll
                for (int kk = 0; kk < 4; ++kk) {
                    const float4* p = (const float4*)(rp + kk * 32);
                    raw[i][kk][0] = p[0];
                    raw[i][kk][1] = p[1];
                }
            }
        }

        // ---- MFMA ----
        f32x4 acc[2][8];
        #pragma unroll
        for (int i = 0; i < 2; ++i)
            #pragma unroll
            for (int cf = 0; cf < 8; ++cf) acc[i][cf] = (f32x4){0.f, 0.f, 0.f, 0.f};

        #pragma unroll
        for (int kk = 0; kk < 4; ++kk) {
            short8 bfrag[8];
            #pragma unroll
            for (int cf = 0; cf < 8; ++cf)
                bfrag[cf] = *(const short8*)(wsb + (size_t)((cf * 4 + kk) * 64 + lane) * 8);
            #pragma unroll
            for (int i = 0; i < 2; ++i)
                #pragma unroll
                for (int cf = 0; cf < 8; ++cf)
                    acc[i][cf] = __builtin_amdgcn_mfma_f32_16x16x32_bf16(
                        afrag[i][kk], bfrag[cf], acc[i][cf], 0, 0, 0);
        }

        // ---- epilogue: bias + LN -> LDS transpose (per-wave, no barrier)
        //      -> coalesced 1KB nontemporal wave-stores ----
        const int rsel = lane >> 5;          // 0/1: which of 2 consecutive rows
        const int c4   = (lane & 31) * 4;    // col start for coalesced read/store

        #pragma unroll
        for (int i = 0; i < 2; ++i) {
            #pragma unroll
            for (int r = 0; r < 4; ++r) {
                float s = 0.f, q = 0.f;
                float zv[8];
                #pragma unroll
                for (int cf = 0; cf < 8; ++cf) {
                    float z = acc[i][cf][r] + bias_v[cf];
                    zv[cf] = z;
                    s += z;
                    q += z * z;
                }
                #pragma unroll
                for (int m = 1; m <= 8; m <<= 1) {
                    s += __shfl_xor(s, m, 64);
                    q += __shfl_xor(q, m, 64);
                }
                float mean = s * (1.0f / 128.0f);
                float var  = q * (1.0f / 128.0f) - mean * mean;
                float rs   = rsqrtf(var + 1e-5f);

                // scatter normalized row-chunk into this wave's LDS tile
                #pragma unroll
                for (int cf = 0; cf < 8; ++cf)
                    tl[wave][lk * 4 + r][cf * 16 + lrow] = (zv[cf] - mean) * rs;
            }

            // read back row-major, store coalesced (1KB contiguous per instr)
            const long rb = row_base + i * 16;
            #pragma unroll
            for (int it = 0; it < 8; ++it) {
                f32x4 v = *(const f32x4*)&tl[wave][2 * it + rsel][c4];
                __builtin_nontemporal_store(
                    v, (f32x4*)(out + (rb + 2 * it + rsel) * D128 + c4));
            }
        }
    }
}

extern "C" void kernel_launch(void* const* d_in, const int* in_sizes, int n_in,
                              void* d_out, int out_size, void* d_ws, size_t ws_size,
                              hipStream_t stream) {
    const float* x    = (const float*)d_in[0];
    const float* w    = (const float*)d_in[1];
    const float* bias = (const float*)d_in[2];
    float* out        = (float*)d_out;

    int nrows  = in_sizes[0] / D128;   // 262144
    int ntiles = nrows / 128;          // 2048
    int grid   = ntiles / 2;           // 1024 blocks, 2 tiles each

    unsigned short* wsb = (unsigned short*)d_ws;
    hipLaunchKernelGGL(convert_w_kernel, dim3(32), dim3(64), 0, stream, w, wsb);
    hipLaunchKernelGGL(fused_linear_ln_kernel, dim3(grid), dim3(256), 0, stream,
                       x, wsb, bias, out, ntiles);
}

// Round 7
// 57.152 us; speedup vs baseline: 3.8536x; 1.0866x over previous
//
#include <hip/hip_runtime.h>

typedef __attribute__((ext_vector_type(8))) short short8;
typedef __attribute__((ext_vector_type(4))) float f32x4;

#define D128 128
#define TSTRIDE 132   // f32 transpose tile row stride: 528B, 16B-aligned, 2-way banks (free)

// fp32 -> bf16 round-to-nearest-even (bit pattern)
__device__ __forceinline__ unsigned short f2bf(float f) {
    unsigned int u = __float_as_uint(f);
    u += 0x7fffu + ((u >> 16) & 1u);
    return (unsigned short)(u >> 16);
}

// ---------------------------------------------------------------------------
// Pre-kernel: convert W (fp32 [k=128][col=128]) into bf16 B-fragments in ws.
// fragment f = cf*4+kk; lane l holds 8 bf16 at ws[(f*64+l)*8] =
// B[k = kk*32 + (l>>4)*8 + j][col = cf*16 + (l&15)]
// ---------------------------------------------------------------------------
__global__ __launch_bounds__(64)
void convert_w_kernel(const float* __restrict__ w, unsigned short* __restrict__ wsb) {
    int t = blockIdx.x * 64 + threadIdx.x;   // 0..2047
    int f = t >> 6;
    int l = t & 63;
    int cf = f >> 2, kk = f & 3;
    int col   = cf * 16 + (l & 15);
    int kbase = kk * 32 + (l >> 4) * 8;
    short8 v;
    #pragma unroll
    for (int j = 0; j < 8; ++j)
        v[j] = (short)f2bf(w[(kbase + j) * D128 + col]);
    *(short8*)(wsb + (size_t)t * 8) = v;
}

// ---------------------------------------------------------------------------
// Main kernel, occupancy-optimized: 16 rows per wave (half the register
// state of the 32-row variant -> 4 waves/SIMD instead of 2). Block = 2
// waves = 32 rows. Epilogue keeps the per-wave LDS transpose + coalesced
// 1KB nontemporal wave-stores from R6.
// ---------------------------------------------------------------------------
__global__ __launch_bounds__(128)
void fused_linear_ln_kernel(const float* __restrict__ x,
                            const unsigned short* __restrict__ wsb,
                            const float* __restrict__ bias,
                            float* __restrict__ out)
{
    __shared__ float tl[2][16][TSTRIDE];   // 16896 B, one 16x128(+pad) tile per wave

    const int tid  = threadIdx.x;
    const int lane = tid & 63;
    const int wave = tid >> 6;
    const int lrow = lane & 15;
    const int lk   = lane >> 4;

    const long row_base = (long)blockIdx.x * 32 + wave * 16;

    // ---- load this wave's 16 rows of x (fp32), cvt to bf16 A fragments ----
    // A frag kk: lane holds A[row_base + lrow][kk*32 + lk*8 + j], j=0..7
    short8 afrag[4];
    {
        const float* rp = x + (row_base + lrow) * D128 + lk * 8;
        #pragma unroll
        for (int kk = 0; kk < 4; ++kk) {
            const float4* p = (const float4*)(rp + kk * 32);
            float4 v0 = p[0];
            float4 v1 = p[1];
            short8 a;
            a[0] = (short)f2bf(v0.x); a[1] = (short)f2bf(v0.y);
            a[2] = (short)f2bf(v0.z); a[3] = (short)f2bf(v0.w);
            a[4] = (short)f2bf(v1.x); a[5] = (short)f2bf(v1.y);
            a[6] = (short)f2bf(v1.z); a[7] = (short)f2bf(v1.w);
            afrag[kk] = a;
        }
    }

    float bias_v[8];
    #pragma unroll
    for (int cf = 0; cf < 8; ++cf) bias_v[cf] = bias[cf * 16 + lrow];

    // ---- MFMA: 4 k-steps x 8 col-fragments ----
    f32x4 acc[8];
    #pragma unroll
    for (int cf = 0; cf < 8; ++cf) acc[cf] = (f32x4){0.f, 0.f, 0.f, 0.f};

    #pragma unroll
    for (int kk = 0; kk < 4; ++kk) {
        short8 bfrag[8];
        #pragma unroll
        for (int cf = 0; cf < 8; ++cf)
            bfrag[cf] = *(const short8*)(wsb + (size_t)((cf * 4 + kk) * 64 + lane) * 8);
        #pragma unroll
        for (int cf = 0; cf < 8; ++cf)
            acc[cf] = __builtin_amdgcn_mfma_f32_16x16x32_bf16(
                afrag[kk], bfrag[cf], acc[cf], 0, 0, 0);
    }

    // ---- epilogue: bias + LN -> per-wave LDS transpose -> coalesced NT stores ----
    #pragma unroll
    for (int r = 0; r < 4; ++r) {
        float s = 0.f, q = 0.f;
        float zv[8];
        #pragma unroll
        for (int cf = 0; cf < 8; ++cf) {
            float z = acc[cf][r] + bias_v[cf];
            zv[cf] = z;
            s += z;
            q += z * z;
        }
        #pragma unroll
        for (int m = 1; m <= 8; m <<= 1) {
            s += __shfl_xor(s, m, 64);
            q += __shfl_xor(q, m, 64);
        }
        float mean = s * (1.0f / 128.0f);
        float var  = q * (1.0f / 128.0f) - mean * mean;
        float rs   = rsqrtf(var + 1e-5f);

        // scatter normalized values into this wave's LDS tile (2-way banks: free)
        #pragma unroll
        for (int cf = 0; cf < 8; ++cf)
            tl[wave][lk * 4 + r][cf * 16 + lrow] = (zv[cf] - mean) * rs;
    }

    // read back row-major, store coalesced (1KB contiguous per instr)
    const int rsel = lane >> 5;          // 0/1: which of 2 consecutive rows
    const int c4   = (lane & 31) * 4;    // col start
    #pragma unroll
    for (int it = 0; it < 8; ++it) {
        f32x4 v = *(const f32x4*)&tl[wave][2 * it + rsel][c4];
        __builtin_nontemporal_store(
            v, (f32x4*)(out + (row_base + 2 * it + rsel) * D128 + c4));
    }
}

extern "C" void kernel_launch(void* const* d_in, const int* in_sizes, int n_in,
                              void* d_out, int out_size, void* d_ws, size_t ws_size,
                              hipStream_t stream) {
    const float* x    = (const float*)d_in[0];
    const float* w    = (const float*)d_in[1];
    const float* bias = (const float*)d_in[2];
    float* out        = (float*)d_out;

    int nrows = in_sizes[0] / D128;    // 262144
    int grid  = nrows / 32;            // 8192 blocks x 32 rows (2 waves x 16)

    unsigned short* wsb = (unsigned short*)d_ws;
    hipLaunchKernelGGL(convert_w_kernel, dim3(32), dim3(64), 0, stream, w, wsb);
    hipLaunchKernelGGL(fused_linear_ln_kernel, dim3(grid), dim3(128), 0, stream,
                       x, wsb, bias, out);
}

// Round 8
// 56.031 us; speedup vs baseline: 3.9307x; 1.0200x over previous
//
#include <hip/hip_runtime.h>

typedef __attribute__((ext_vector_type(8))) short short8;
typedef __attribute__((ext_vector_type(4))) float f32x4;

#define D128 128
#define TSTRIDE 136   // f32 row stride for 4-row store buffer: 544B, 16B-aligned,
                      // 136%32==8 -> lk groups land 8 banks apart -> exact 2-way (free)

// fp32 -> bf16 round-to-nearest-even (bit pattern)
__device__ __forceinline__ unsigned short f2bf(float f) {
    unsigned int u = __float_as_uint(f);
    u += 0x7fffu + ((u >> 16) & 1u);
    return (unsigned short)(u >> 16);
}

// ---------------------------------------------------------------------------
// Pre-kernel: convert W (fp32 [k=128][col=128]) into bf16 B-fragments in ws.
// fragment f = cf*4+kk; lane l holds 8 bf16 at ws[(f*64+l)*8] =
// B[k = kk*32 + (l>>4)*8 + j][col = cf*16 + (l&15)]
// ---------------------------------------------------------------------------
__global__ __launch_bounds__(64)
void convert_w_kernel(const float* __restrict__ w, unsigned short* __restrict__ wsb) {
    int t = blockIdx.x * 64 + threadIdx.x;   // 0..2047
    int f = t >> 6;
    int l = t & 63;
    int cf = f >> 2, kk = f & 3;
    int col   = cf * 16 + (l & 15);
    int kbase = kk * 32 + (l >> 4) * 8;
    short8 v;
    #pragma unroll
    for (int j = 0; j < 8; ++j)
        v[j] = (short)f2bf(w[(kbase + j) * D128 + col]);
    *(short8*)(wsb + (size_t)t * 8) = v;
}

// ---------------------------------------------------------------------------
// Main kernel. 16 rows/wave, block = 2 waves = 32 rows. Tiny per-r LDS
// staging: each LN iteration finishes 4 rows (one per lk group); they are
// scattered to a 4x128(+pad) f32 buffer and immediately stored as two
// coalesced 2-row nontemporal wave-stores. LDS/block = 4.3KB -> blocks/CU
// hits the HW cap (16) instead of the LDS cap, ~2x resident waves vs R7,
// and stores are spread through the epilogue (fewer write-pipe gaps).
// ---------------------------------------------------------------------------
__global__ __launch_bounds__(128)
void fused_linear_ln_kernel(const float* __restrict__ x,
                            const unsigned short* __restrict__ wsb,
                            const float* __restrict__ bias,
                            float* __restrict__ out)
{
    __shared__ float tlb[2][4][TSTRIDE];   // 4352 B

    const int tid  = threadIdx.x;
    const int lane = tid & 63;
    const int wave = tid >> 6;
    const int lrow = lane & 15;
    const int lk   = lane >> 4;

    const long row_base = (long)blockIdx.x * 32 + wave * 16;

    // ---- load this wave's 16 rows of x (fp32), cvt to bf16 A fragments ----
    short8 afrag[4];
    {
        const float* rp = x + (row_base + lrow) * D128 + lk * 8;
        #pragma unroll
        for (int kk = 0; kk < 4; ++kk) {
            const float4* p = (const float4*)(rp + kk * 32);
            float4 v0 = p[0];
            float4 v1 = p[1];
            short8 a;
            a[0] = (short)f2bf(v0.x); a[1] = (short)f2bf(v0.y);
            a[2] = (short)f2bf(v0.z); a[3] = (short)f2bf(v0.w);
            a[4] = (short)f2bf(v1.x); a[5] = (short)f2bf(v1.y);
            a[6] = (short)f2bf(v1.z); a[7] = (short)f2bf(v1.w);
            afrag[kk] = a;
        }
    }

    float bias_v[8];
    #pragma unroll
    for (int cf = 0; cf < 8; ++cf) bias_v[cf] = bias[cf * 16 + lrow];

    // ---- MFMA: 4 k-steps x 8 col-fragments ----
    f32x4 acc[8];
    #pragma unroll
    for (int cf = 0; cf < 8; ++cf) acc[cf] = (f32x4){0.f, 0.f, 0.f, 0.f};

    #pragma unroll
    for (int kk = 0; kk < 4; ++kk) {
        short8 bfrag[8];
        #pragma unroll
        for (int cf = 0; cf < 8; ++cf)
            bfrag[cf] = *(const short8*)(wsb + (size_t)((cf * 4 + kk) * 64 + lane) * 8);
        #pragma unroll
        for (int cf = 0; cf < 8; ++cf)
            acc[cf] = __builtin_amdgcn_mfma_f32_16x16x32_bf16(
                afrag[kk], bfrag[cf], acc[cf], 0, 0, 0);
    }

    // ---- epilogue: per r, finish 4 rows (one per lk group), stage in tiny
    //      LDS buffer, store immediately as 2 coalesced NT wave-stores ----
    const int rsel = lane >> 5;          // 0/1
    const int c4   = (lane & 31) * 4;    // col start for read-back/store

    #pragma unroll
    for (int r = 0; r < 4; ++r) {
        float s = 0.f, q = 0.f;
        float zv[8];
        #pragma unroll
        for (int cf = 0; cf < 8; ++cf) {
            float z = acc[cf][r] + bias_v[cf];
            zv[cf] = z;
            s += z;
            q += z * z;
        }
        #pragma unroll
        for (int m = 1; m <= 8; m <<= 1) {
            s += __shfl_xor(s, m, 64);
            q += __shfl_xor(q, m, 64);
        }
        float mean = s * (1.0f / 128.0f);
        float var  = q * (1.0f / 128.0f) - mean * mean;
        float rs   = rsqrtf(var + 1e-5f);

        // lk group holds output row (row_base + lk*4 + r): scatter into buffer row lk
        #pragma unroll
        for (int cf = 0; cf < 8; ++cf)
            tlb[wave][lk][cf * 16 + lrow] = (zv[cf] - mean) * rs;

        // store buffer rows 0..3 -> output rows row_base + 4*j + r
        #pragma unroll
        for (int i2 = 0; i2 < 2; ++i2) {
            int j = i2 * 2 + rsel;
            f32x4 v = *(const f32x4*)&tlb[wave][j][c4];
            __builtin_nontemporal_store(
                v, (f32x4*)(out + (row_base + 4 * j + r) * D128 + c4));
        }
    }
}

extern "C" void kernel_launch(void* const* d_in, const int* in_sizes, int n_in,
                              void* d_out, int out_size, void* d_ws, size_t ws_size,
                              hipStream_t stream) {
    const float* x    = (const float*)d_in[0];
    const float* w    = (const float*)d_in[1];
    const float* bias = (const float*)d_in[2];
    float* out        = (float*)d_out;

    int nrows = in_sizes[0] / D128;    // 262144
    int grid  = nrows / 32;            // 8192 blocks x 32 rows (2 waves x 16)

    unsigned short* wsb = (unsigned short*)d_ws;
    hipLaunchKernelGGL(convert_w_kernel, dim3(32), dim3(64), 0, stream, w, wsb);
    hipLaunchKernelGGL(fused_linear_ln_kernel, dim3(grid), dim3(128), 0, stream,
                       x, wsb, bias, out);
}